// Round 3
// baseline (354.551 us; speedup 1.0000x reference)
//
#include <hip/hip_runtime.h>
#include <stdint.h>

typedef __bf16 bf16;
typedef __bf16 bf16x8 __attribute__((ext_vector_type(8)));
typedef __bf16 bf16x4 __attribute__((ext_vector_type(4)));
typedef float  f32x4  __attribute__((ext_vector_type(4)));
typedef float  f32x16 __attribute__((ext_vector_type(16)));
typedef float  float4v __attribute__((ext_vector_type(4)));
typedef unsigned int uint;
typedef unsigned long long ull;

// log2(e)/sqrt(32): folds softmax 1/sqrt(Dh) and e^x -> 2^x into Q scaling
#define QSCALE 0.25505003984214403f

// ---------------- K0: transpose weights -> bf16 WT[w][n][k] ----------------
__global__ __launch_bounds__(256) void transpose_w(
    const float* __restrict__ w0, const float* __restrict__ w1,
    const float* __restrict__ w2, const float* __restrict__ w3,
    bf16* __restrict__ WT) {
  const int wsel = blockIdx.z;
  const float* W = wsel == 0 ? w0 : wsel == 1 ? w1 : wsel == 2 ? w2 : w3;
  const int k0 = blockIdx.x * 64, n0 = blockIdx.y * 64;
  __shared__ __align__(16) bf16 t[64][72];
  const int tid = threadIdx.x;
  {
    const int kk = (tid >> 4) << 2;
    const int nn = (tid & 15) << 2;
#pragma unroll
    for (int r = 0; r < 4; ++r) {
      float4v a = *(const float4v*)(W + (size_t)(k0 + kk + r) * 256 + n0 + nn);
#pragma unroll
      for (int j = 0; j < 4; ++j) t[nn + j][kk + r] = (bf16)a[j];
    }
  }
  __syncthreads();
  {
    const int ni = tid >> 2;
    const int c  = (tid & 3) * 16;
    bf16x8 o0 = *(const bf16x8*)(&t[ni][c]);
    bf16x8 o1 = *(const bf16x8*)(&t[ni][c + 8]);
    bf16* dst = WT + (size_t)wsel * 65536 + (size_t)(n0 + ni) * 256 + k0 + c;
    *(bf16x8*)dst = o0;
    *(bf16x8*)(dst + 8) = o1;
  }
}

// ---------------- K1: fused proj (blocks 0..767) + pack_mask (768..8959) ----
// pack_mask output TRANSPOSED: bit q of M2[(b*128 + kdw)*4096 + q] = mask[b][q][kdw*32+bit]
__global__ __launch_bounds__(256) void proj_pack(
    const float* __restrict__ xq, const float* __restrict__ xk, const float* __restrict__ xv,
    const bf16* __restrict__ WT,
    bf16* __restrict__ Qo, bf16* __restrict__ Ko, bf16* __restrict__ Vt,
    const int* __restrict__ mask, uint* __restrict__ M2) {
  const int tid = threadIdx.x;
  if (blockIdx.x >= 768) {
    // ---- pack_mask part ----
    const int pid = blockIdx.x - 768;
    const int wid = pid * 4 + (tid >> 6);   // [0, 32768): (b*4096+q)*4 + chunk
    const int lane = tid & 63;
    const int row = wid >> 2, chunk = wid & 3;
    const int b = row >> 12, q = row & 4095;
    const size_t base = (size_t)row * 4096 + chunk * 1024 + lane;
    ull bl[16];
#pragma unroll
    for (int j = 0; j < 16; ++j) bl[j] = __ballot(mask[base + 64 * j] != 0);
    if (lane == 0) {
      uint* o = M2 + (size_t)b * 524288 + q;
#pragma unroll
      for (int j = 0; j < 16; ++j) {
        const int kdw = chunk * 32 + 2 * j;
        o[(size_t)kdw * 4096] = (uint)bl[j];
        o[(size_t)(kdw + 1) * 4096] = (uint)(bl[j] >> 32);
      }
    }
    return;
  }
  // ---- proj part ----
  const int z = blockIdx.x >> 8;            // 0..2
  const int r8 = blockIdx.x & 255;
  const int m0 = (r8 >> 1) * 64, n0 = (r8 & 1) * 128;
  const float* X = z == 0 ? xq : (z == 1 ? xk : xv);
  const bf16* wt = WT + (size_t)z * 65536;
  const int wave = tid >> 6, lane = tid & 63;
  const int nl = lane & 15, quad = lane >> 4;
  const int arow = m0 + wave * 16 + nl;
  const float* xrow = X + (size_t)arow * 256;

  f32x4 zero4 = {0.f, 0.f, 0.f, 0.f};
  f32x4 acc[8];
#pragma unroll
  for (int i = 0; i < 8; ++i) acc[i] = zero4;

  for (int ks = 0; ks < 8; ++ks) {
    float4v a0 = *(const float4v*)(xrow + ks * 32 + quad * 8);
    float4v a1 = *(const float4v*)(xrow + ks * 32 + quad * 8 + 4);
    bf16x8 af;
#pragma unroll
    for (int i = 0; i < 4; ++i) { af[i] = (bf16)a0[i]; af[4 + i] = (bf16)a1[i]; }
#pragma unroll
    for (int nf = 0; nf < 8; ++nf) {
      bf16x8 bfr = *(const bf16x8*)(wt + (size_t)(n0 + nf * 16 + nl) * 256 + ks * 32 + quad * 8);
      acc[nf] = __builtin_amdgcn_mfma_f32_16x16x32_bf16(af, bfr, acc[nf], 0, 0, 0);
    }
  }

  const int Rbase = m0 + wave * 16 + quad * 4;
  if (z == 2) {
    const int b = Rbase >> 12, s = Rbase & 4095;
#pragma unroll
    for (int nf = 0; nf < 8; ++nf) {
      const int col = n0 + nf * 16 + nl;
      const int h = col >> 5, d = col & 31;
      bf16x4 o;
#pragma unroll
      for (int rr = 0; rr < 4; ++rr) o[rr] = (bf16)acc[nf][rr];
      *(bf16x4*)(Vt + (((size_t)(b * 8 + h)) * 32 + d) * 4096 + s) = o;
    }
  } else {
    const float scale = (z == 0) ? QSCALE : 1.0f;
    bf16* Out = z == 0 ? Qo : Ko;
#pragma unroll
    for (int nf = 0; nf < 8; ++nf) {
      const int col = n0 + nf * 16 + nl;
      const int h = col >> 5, d = col & 31;
#pragma unroll
      for (int rr = 0; rr < 4; ++rr) {
        const int R = Rbase + rr;
        const int b = R >> 12, s = R & 4095;
        Out[(((size_t)(b * 8 + h)) * 4096 + s) * 32 + d] = (bf16)(acc[nf][rr] * scale);
      }
    }
  }
}

// ---------------- K3: attention — 32x32x16 MFMA, zero LDS / zero barriers in K-loop
// Wave w handles keys [kt*128+w*32, +32) for all 64 q of the block.
// S^T C-layout (key=row, q=col) is re-used DIRECTLY as PV B-operand via the
// key permutation key = s*16 + half*4 + (j&3) + 8*(j>>2); V A-frags load global
// in that order. LDS only for the cross-wave O / lsum reduction at the end.
__global__ __launch_bounds__(256) void attn_kernel(
    const bf16* __restrict__ Qg, const bf16* __restrict__ Kg,
    const bf16* __restrict__ Vtg, const uint* __restrict__ M2,
    bf16* __restrict__ Og) {
  const int bh = blockIdx.y, b = bh >> 3, h = bh & 7;
  const int q0 = blockIdx.x * 64;
  const int tid = threadIdx.x, w = tid >> 6, lane = tid & 63;
  const int nl = lane & 31, half = lane >> 5;

  __shared__ float Ored[4][32][66];   // [wave][d][q], pitch 66
  __shared__ float Lsum[64][8];       // [q][w*2+half]

  // Q B-frags (registers, whole kernel): qf[qt][s] = Q[q0+qt*32+nl][s*16+half*8+j]
  bf16x8 qf[2][2];
  {
    const bf16* Qbase = Qg + ((size_t)bh * 4096 + q0) * 32;
#pragma unroll
    for (int qt = 0; qt < 2; ++qt)
#pragma unroll
      for (int s = 0; s < 2; ++s)
        qf[qt][s] = *(const bf16x8*)(Qbase + (size_t)(qt * 32 + nl) * 32 + s * 16 + half * 8);
  }

  const bf16* Kbase = Kg + (size_t)bh * 4096 * 32 + (size_t)(w * 32 + nl) * 32;
  const bf16* Vbase = Vtg + ((size_t)bh * 32 + nl) * 4096 + w * 32 + half * 4;
  const uint* Mbase = M2 + (size_t)b * 524288 + q0 + nl;

  f32x16 acc0, acc1;
#pragma unroll
  for (int i = 0; i < 16; ++i) { acc0[i] = 0.f; acc1[i] = 0.f; }
  float lsum0 = 0.f, lsum1 = 0.f;

  for (int kt = 0; kt < 32; ++kt) {
    // K A-frags: ka[s] = K[kt*128+w*32+nl][s*16+half*8+j]  (coalesced b128)
    const bf16* kc = Kbase + (size_t)kt * 4096;
    bf16x8 ka0 = *(const bf16x8*)(kc + half * 8);
    bf16x8 ka1 = *(const bf16x8*)(kc + 16 + half * 8);
    // V A-frags in permuted key order: va[s][j] = V[d=nl][s*16+half*4+(j&3)+8*(j>>2)]
    const bf16* vc = Vbase + (size_t)kt * 128;
    bf16x4 v00 = *(const bf16x4*)(vc);
    bf16x4 v01 = *(const bf16x4*)(vc + 8);
    bf16x4 v10 = *(const bf16x4*)(vc + 16);
    bf16x4 v11 = *(const bf16x4*)(vc + 24);
    bf16x8 va0, va1;
#pragma unroll
    for (int j = 0; j < 4; ++j) {
      va0[j] = v00[j]; va0[4 + j] = v01[j];
      va1[j] = v10[j]; va1[4 + j] = v11[j];
    }
    // mask dwords (transposed layout: lane-coalesced)
    const uint* mp = Mbase + (size_t)(kt * 4 + w) * 4096;
    const int minv0 = (int)((~mp[0]) >> (4 * half));
    const int minv1 = (int)((~mp[32]) >> (4 * half));

    // S^T = K . Q^T : rows key(32), cols q(32) per qt
    f32x16 z16;
#pragma unroll
    for (int i = 0; i < 16; ++i) z16[i] = 0.f;
    f32x16 st0 = __builtin_amdgcn_mfma_f32_32x32x16_bf16(ka0, qf[0][0], z16, 0, 0, 0);
    st0 = __builtin_amdgcn_mfma_f32_32x32x16_bf16(ka1, qf[0][1], st0, 0, 0, 0);
    f32x16 st1 = __builtin_amdgcn_mfma_f32_32x32x16_bf16(ka0, qf[1][0], z16, 0, 0, 0);
    st1 = __builtin_amdgcn_mfma_f32_32x32x16_bf16(ka1, qf[1][1], st1, 0, 0, 0);

    // p = 2^s masked; reg g*4+r holds key r+8g+4half; pack pairs -> PV B-frags
    bf16 pe0[16], pe1[16];
#pragma unroll
    for (int g = 0; g < 4; ++g)
#pragma unroll
      for (int r = 0; r < 4; ++r) {
        const int i = g * 4 + r, off = r + 8 * g;
        float e0 = __builtin_amdgcn_exp2f(st0[i]);
        float e1 = __builtin_amdgcn_exp2f(st1[i]);
        const uint k0m = (uint)__builtin_amdgcn_sbfe(minv0, off, 1);
        const uint k1m = (uint)__builtin_amdgcn_sbfe(minv1, off, 1);
        e0 = __uint_as_float(__float_as_uint(e0) & k0m);
        e1 = __uint_as_float(__float_as_uint(e1) & k1m);
        lsum0 += e0; lsum1 += e1;
        pe0[i] = (bf16)e0; pe1[i] = (bf16)e1;
      }
    const bf16x8 pb00 = *(const bf16x8*)&pe0[0];
    const bf16x8 pb01 = *(const bf16x8*)&pe0[8];
    const bf16x8 pb10 = *(const bf16x8*)&pe1[0];
    const bf16x8 pb11 = *(const bf16x8*)&pe1[8];

    // O^T += V . P : rows d(32), cols q(32) per qt
    acc0 = __builtin_amdgcn_mfma_f32_32x32x16_bf16(va0, pb00, acc0, 0, 0, 0);
    acc0 = __builtin_amdgcn_mfma_f32_32x32x16_bf16(va1, pb01, acc0, 0, 0, 0);
    acc1 = __builtin_amdgcn_mfma_f32_32x32x16_bf16(va0, pb10, acc1, 0, 0, 0);
    acc1 = __builtin_amdgcn_mfma_f32_32x32x16_bf16(va1, pb11, acc1, 0, 0, 0);
  }

  // ---- epilogue: cross-wave reduce (one-time LDS) ----
#pragma unroll
  for (int g = 0; g < 4; ++g)
#pragma unroll
    for (int r = 0; r < 4; ++r) {
      const int d = r + 8 * g + 4 * half, i = g * 4 + r;
      Ored[w][d][nl] = acc0[i];
      Ored[w][d][32 + nl] = acc1[i];
    }
  Lsum[nl][w * 2 + half] = lsum0;
  Lsum[32 + nl][w * 2 + half] = lsum1;
  __syncthreads();
  if (tid < 64) {
    float s = 0.f;
#pragma unroll
    for (int j = 0; j < 8; ++j) s += Lsum[tid][j];
    Lsum[tid][0] = 1.0f / s;
  }
  __syncthreads();
  {
    const int q = tid >> 2, db = (tid & 3) * 8;
    const float rl = Lsum[q][0];
    bf16x8 o;
#pragma unroll
    for (int dj = 0; dj < 8; ++dj) {
      const float s = Ored[0][db + dj][q] + Ored[1][db + dj][q] +
                      Ored[2][db + dj][q] + Ored[3][db + dj][q];
      o[dj] = (bf16)(s * rl);
    }
    *(bf16x8*)(Og + ((size_t)(b * 4096 + q0 + q)) * 256 + h * 32 + db) = o;
  }
}

// ---------------- K4: out = attn(bf16) @ w_out -> fp32 ----------------
__global__ __launch_bounds__(256) void gemm_out(
    const bf16* __restrict__ A, const bf16* __restrict__ WTo, float* __restrict__ C) {
  const int m0 = blockIdx.x * 64, n0 = blockIdx.y * 128;
  const int tid = threadIdx.x, wave = tid >> 6, lane = tid & 63;
  const int nl = lane & 15, quad = lane >> 4;
  const int arow = m0 + wave * 16 + nl;

  f32x4 zero4 = {0.f, 0.f, 0.f, 0.f};
  f32x4 acc[8];
#pragma unroll
  for (int i = 0; i < 8; ++i) acc[i] = zero4;

  for (int ks = 0; ks < 8; ++ks) {
    bf16x8 af = *(const bf16x8*)(A + (size_t)arow * 256 + ks * 32 + quad * 8);
#pragma unroll
    for (int nf = 0; nf < 8; ++nf) {
      bf16x8 bfr = *(const bf16x8*)(WTo + (size_t)(n0 + nf * 16 + nl) * 256 + ks * 32 + quad * 8);
      acc[nf] = __builtin_amdgcn_mfma_f32_16x16x32_bf16(af, bfr, acc[nf], 0, 0, 0);
    }
  }
  const int Rbase = m0 + wave * 16 + quad * 4;
#pragma unroll
  for (int nf = 0; nf < 8; ++nf)
#pragma unroll
    for (int r = 0; r < 4; ++r)
      C[(size_t)(Rbase + r) * 256 + n0 + nf * 16 + nl] = acc[nf][r];
}

extern "C" void kernel_launch(void* const* d_in, const int* in_sizes, int n_in,
                              void* d_out, int out_size, void* d_ws, size_t ws_size,
                              hipStream_t stream) {
  const float* q  = (const float*)d_in[0];
  const float* k  = (const float*)d_in[1];
  const float* v  = (const float*)d_in[2];
  const int*  mask = (const int*)d_in[3];
  const float* wq = (const float*)d_in[4];
  const float* wk = (const float*)d_in[5];
  const float* wv = (const float*)d_in[6];
  const float* wo = (const float*)d_in[7];
  float* out = (float*)d_out;

  uint8_t* ws = (uint8_t*)d_ws;
  bf16* WT = (bf16*)ws;                               // 512 KB
  bf16* Qb = (bf16*)(ws + (512u << 10));              // [B,H,S,32] 4 MB
  bf16* Kb = Qb + 2097152;                            // [B,H,S,32] 4 MB
  bf16* Vt = Kb + 2097152;                            // [B,H,32,S] 4 MB
  uint* Mb = (uint*)((uint8_t*)(Vt + 2097152));       // transposed packed mask 4 MB
  bf16* Ao = (bf16*)((uint8_t*)Mb + (4u << 20));      // attn bf16 [B,S,256] 4 MB

  transpose_w<<<dim3(4, 4, 4), 256, 0, stream>>>(wq, wk, wv, wo, WT);
  proj_pack<<<dim3(768 + 8192), 256, 0, stream>>>(q, k, v, WT, Qb, Kb, Vt, mask, Mb);
  attn_kernel<<<dim3(64, 16), 256, 0, stream>>>(Qb, Kb, Vt, Mb, Ao);
  gemm_out<<<dim3(128, 2), 256, 0, stream>>>(Ao, WT + 3 * 65536, out);
}

// Round 4
// 329.665 us; speedup vs baseline: 1.0755x; 1.0755x over previous
//
#include <hip/hip_runtime.h>
#include <stdint.h>

typedef __bf16 bf16;
typedef __bf16 bf16x8 __attribute__((ext_vector_type(8)));
typedef __bf16 bf16x4 __attribute__((ext_vector_type(4)));
typedef float  f32x4  __attribute__((ext_vector_type(4)));
typedef float  f32x16 __attribute__((ext_vector_type(16)));
typedef float  float4v __attribute__((ext_vector_type(4)));
typedef unsigned int uint;
typedef unsigned long long ull;

// log2(e)/sqrt(32): folds softmax 1/sqrt(Dh) and e^x -> 2^x into Q scaling
#define QSCALE 0.25505003984214403f

// Fragment-native tensor layout for attn: [bh][blk(128)][sub(4)][lane(32)][8]
//  Q/K: element (pos, d) -> blk=pos>>5, sub=d>>3, lane=pos&31, j=d&7
//  V  : element (key, d) -> blk=key>>5, sub=((key5>>4)<<1)|((key5>>2)&1),
//                           lane=d, j = ((key5>>3)&1)*4 + (key5&3)   (key5=key&31)
// so every attn wave load is base + lane*16B (fully coalesced 1KB).

// ---------------- K0: transpose weights -> bf16 WT[w][n][k] ----------------
__global__ __launch_bounds__(256) void transpose_w(
    const float* __restrict__ w0, const float* __restrict__ w1,
    const float* __restrict__ w2, const float* __restrict__ w3,
    bf16* __restrict__ WT) {
  const int wsel = blockIdx.z;
  const float* W = wsel == 0 ? w0 : wsel == 1 ? w1 : wsel == 2 ? w2 : w3;
  const int k0 = blockIdx.x * 64, n0 = blockIdx.y * 64;
  __shared__ __align__(16) bf16 t[64][72];
  const int tid = threadIdx.x;
  {
    const int kk = (tid >> 4) << 2;
    const int nn = (tid & 15) << 2;
#pragma unroll
    for (int r = 0; r < 4; ++r) {
      float4v a = *(const float4v*)(W + (size_t)(k0 + kk + r) * 256 + n0 + nn);
#pragma unroll
      for (int j = 0; j < 4; ++j) t[nn + j][kk + r] = (bf16)a[j];
    }
  }
  __syncthreads();
  {
    const int ni = tid >> 2;
    const int c  = (tid & 3) * 16;
    bf16x8 o0 = *(const bf16x8*)(&t[ni][c]);
    bf16x8 o1 = *(const bf16x8*)(&t[ni][c + 8]);
    bf16* dst = WT + (size_t)wsel * 65536 + (size_t)(n0 + ni) * 256 + k0 + c;
    *(bf16x8*)dst = o0;
    *(bf16x8*)(dst + 8) = o1;
  }
}

// ---------------- K1: fused proj (blocks 0..767) + pack_mask (768..8959) ----
// mask packed TRANSPOSED: bit q of M2[(b*128 + kdw)*4096 + q] = mask[b][q][kdw*32+bit]
__global__ __launch_bounds__(256) void proj_pack(
    const float* __restrict__ xq, const float* __restrict__ xk, const float* __restrict__ xv,
    const bf16* __restrict__ WT,
    bf16* __restrict__ Qp, bf16* __restrict__ Kp, bf16* __restrict__ Vp,
    const int* __restrict__ mask, uint* __restrict__ M2) {
  const int tid = threadIdx.x;
  if (blockIdx.x >= 768) {
    const int pid = blockIdx.x - 768;
    const int wid = pid * 4 + (tid >> 6);
    const int lane = tid & 63;
    const int row = wid >> 2, chunk = wid & 3;
    const int b = row >> 12, q = row & 4095;
    const size_t base = (size_t)row * 4096 + chunk * 1024 + lane;
    ull bl[16];
#pragma unroll
    for (int j = 0; j < 16; ++j) bl[j] = __ballot(mask[base + 64 * j] != 0);
    if (lane == 0) {
      uint* o = M2 + (size_t)b * 524288 + q;
#pragma unroll
      for (int j = 0; j < 16; ++j) {
        const int kdw = chunk * 32 + 2 * j;
        o[(size_t)kdw * 4096] = (uint)bl[j];
        o[(size_t)(kdw + 1) * 4096] = (uint)(bl[j] >> 32);
      }
    }
    return;
  }
  // ---- proj part ----
  const int z = blockIdx.x >> 8;
  const int r8 = blockIdx.x & 255;
  const int m0 = (r8 >> 1) * 64, n0 = (r8 & 1) * 128;
  const float* X = z == 0 ? xq : (z == 1 ? xk : xv);
  const bf16* wt = WT + (size_t)z * 65536;
  const int wave = tid >> 6, lane = tid & 63;
  const int nl = lane & 15, quad = lane >> 4;
  const int arow = m0 + wave * 16 + nl;
  const float* xrow = X + (size_t)arow * 256;

  f32x4 zero4 = {0.f, 0.f, 0.f, 0.f};
  f32x4 acc[8];
#pragma unroll
  for (int i = 0; i < 8; ++i) acc[i] = zero4;

  for (int ks = 0; ks < 8; ++ks) {
    float4v a0 = *(const float4v*)(xrow + ks * 32 + quad * 8);
    float4v a1 = *(const float4v*)(xrow + ks * 32 + quad * 8 + 4);
    bf16x8 af;
#pragma unroll
    for (int i = 0; i < 4; ++i) { af[i] = (bf16)a0[i]; af[4 + i] = (bf16)a1[i]; }
#pragma unroll
    for (int nf = 0; nf < 8; ++nf) {
      bf16x8 bfr = *(const bf16x8*)(wt + (size_t)(n0 + nf * 16 + nl) * 256 + ks * 32 + quad * 8);
      acc[nf] = __builtin_amdgcn_mfma_f32_16x16x32_bf16(af, bfr, acc[nf], 0, 0, 0);
    }
  }

  const int Rbase = m0 + wave * 16 + quad * 4;
  if (z == 2) {
    // V fragment-native: 4 consecutive keys (r=0..3) -> contiguous j -> bf16x4
    const int b = Rbase >> 12, key = Rbase & 4095;
    const int key5 = key & 31;
    const int sub = ((key5 >> 4) << 1) | ((key5 >> 2) & 1);
    const int g = (key5 >> 3) & 1;
#pragma unroll
    for (int nf = 0; nf < 8; ++nf) {
      const int col = n0 + nf * 16 + nl;
      const int h = col >> 5, d = col & 31;
      bf16x4 o;
#pragma unroll
      for (int rr = 0; rr < 4; ++rr) o[rr] = (bf16)acc[nf][rr];
      const size_t off = (size_t)(b * 8 + h) * 131072 + (size_t)(key >> 5) * 1024 +
                         sub * 256 + d * 8 + g * 4;
      *(bf16x4*)(Vp + off) = o;
    }
  } else {
    const float scale = (z == 0) ? QSCALE : 1.0f;
    bf16* Out = z == 0 ? Qp : Kp;
#pragma unroll
    for (int nf = 0; nf < 8; ++nf) {
      const int col = n0 + nf * 16 + nl;
      const int h = col >> 5, d = col & 31;
      const int sub = d >> 3, j = d & 7;
#pragma unroll
      for (int rr = 0; rr < 4; ++rr) {
        const int R = Rbase + rr;
        const int b = R >> 12, sidx = R & 4095;
        const size_t off = (size_t)(b * 8 + h) * 131072 + (size_t)(sidx >> 5) * 1024 +
                           sub * 256 + (sidx & 31) * 8 + j;
        Out[off] = (bf16)(acc[nf][rr] * scale);
      }
    }
  }
}

// ---------------- K3: attention — 32x32x16, zero LDS in K-loop,
// XCD-swizzled bh, fragment-native coalesced loads, reg double-buffer prefetch.
__global__ __launch_bounds__(256) void attn_kernel(
    const bf16* __restrict__ Qp, const bf16* __restrict__ Kp,
    const bf16* __restrict__ Vp, const uint* __restrict__ M2,
    bf16* __restrict__ Og) {
  const int id = blockIdx.x;
  const int xcd = id & 7, slot = id >> 3;
  const int bh = xcd * 2 + (slot >> 6);      // each XCD: 2 bh -> L2 working set ~3MB
  const int q0 = (slot & 63) * 64;
  const int b = bh >> 3, h = bh & 7;
  const int tid = threadIdx.x, w = tid >> 6, lane = tid & 63;
  const int nl = lane & 31, half = lane >> 5;

  __shared__ float Ored[4][32][66];
  __shared__ float Lsum[64][8];

  const size_t bhbase = (size_t)bh * 131072;
  const int so0 = half * 256 + nl * 8;        // sub = 0*2+half
  const int so1 = 512 + half * 256 + nl * 8;  // sub = 1*2+half

  bf16x8 qf[2][2];
#pragma unroll
  for (int qt = 0; qt < 2; ++qt) {
    const bf16* qb = Qp + bhbase + (size_t)((q0 >> 5) + qt) * 1024;
    qf[qt][0] = *(const bf16x8*)(qb + so0);
    qf[qt][1] = *(const bf16x8*)(qb + so1);
  }

  const bf16* Kw = Kp + bhbase + (size_t)w * 1024;
  const bf16* Vw = Vp + bhbase + (size_t)w * 1024;
  const uint* Mw = M2 + (size_t)b * 524288 + (size_t)w * 4096 + q0 + nl;

  f32x16 z16;
#pragma unroll
  for (int i = 0; i < 16; ++i) z16[i] = 0.f;
  f32x16 acc0 = z16, acc1 = z16;
  float lsum0 = 0.f, lsum1 = 0.f;

  struct Frag { bf16x8 ka0, ka1, va0, va1; uint m0, m1; };
  auto LOADF = [&](int kt) -> Frag {
    Frag f;
    const bf16* kc = Kw + (size_t)kt * 4096;
    const bf16* vc = Vw + (size_t)kt * 4096;
    f.ka0 = *(const bf16x8*)(kc + so0);
    f.ka1 = *(const bf16x8*)(kc + so1);
    f.va0 = *(const bf16x8*)(vc + so0);
    f.va1 = *(const bf16x8*)(vc + so1);
    const uint* mp = Mw + (size_t)kt * 16384;
    f.m0 = mp[0];
    f.m1 = mp[32];
    return f;
  };

  auto STEP = [&](const Frag& f) {
    const int minv0 = (int)((~f.m0) >> (4 * half));
    const int minv1 = (int)((~f.m1) >> (4 * half));
    f32x16 st0 = __builtin_amdgcn_mfma_f32_32x32x16_bf16(f.ka0, qf[0][0], z16, 0, 0, 0);
    st0 = __builtin_amdgcn_mfma_f32_32x32x16_bf16(f.ka1, qf[0][1], st0, 0, 0, 0);
    f32x16 st1 = __builtin_amdgcn_mfma_f32_32x32x16_bf16(f.ka0, qf[1][0], z16, 0, 0, 0);
    st1 = __builtin_amdgcn_mfma_f32_32x32x16_bf16(f.ka1, qf[1][1], st1, 0, 0, 0);

    bf16 pe0[16], pe1[16];
#pragma unroll
    for (int g = 0; g < 4; ++g)
#pragma unroll
      for (int r = 0; r < 4; ++r) {
        const int i = g * 4 + r, off = r + 8 * g;
        float e0 = __builtin_amdgcn_exp2f(st0[i]);
        float e1 = __builtin_amdgcn_exp2f(st1[i]);
        const uint k0m = (uint)__builtin_amdgcn_sbfe(minv0, off, 1);
        const uint k1m = (uint)__builtin_amdgcn_sbfe(minv1, off, 1);
        e0 = __uint_as_float(__float_as_uint(e0) & k0m);
        e1 = __uint_as_float(__float_as_uint(e1) & k1m);
        lsum0 += e0; lsum1 += e1;
        pe0[i] = (bf16)e0; pe1[i] = (bf16)e1;
      }
    const bf16x8 pb00 = *(const bf16x8*)&pe0[0];
    const bf16x8 pb01 = *(const bf16x8*)&pe0[8];
    const bf16x8 pb10 = *(const bf16x8*)&pe1[0];
    const bf16x8 pb11 = *(const bf16x8*)&pe1[8];

    acc0 = __builtin_amdgcn_mfma_f32_32x32x16_bf16(f.va0, pb00, acc0, 0, 0, 0);
    acc0 = __builtin_amdgcn_mfma_f32_32x32x16_bf16(f.va1, pb01, acc0, 0, 0, 0);
    acc1 = __builtin_amdgcn_mfma_f32_32x32x16_bf16(f.va0, pb10, acc1, 0, 0, 0);
    acc1 = __builtin_amdgcn_mfma_f32_32x32x16_bf16(f.va1, pb11, acc1, 0, 0, 0);
  };

  Frag fa = LOADF(0), fb;
  for (int kt = 0; kt < 32; kt += 2) {
    fb = LOADF(kt + 1);
    STEP(fa);
    if (kt + 2 < 32) fa = LOADF(kt + 2);
    STEP(fb);
  }

  // ---- epilogue: cross-wave reduce ----
#pragma unroll
  for (int g = 0; g < 4; ++g)
#pragma unroll
    for (int r = 0; r < 4; ++r) {
      const int d = r + 8 * g + 4 * half, i = g * 4 + r;
      Ored[w][d][nl] = acc0[i];
      Ored[w][d][32 + nl] = acc1[i];
    }
  Lsum[nl][w * 2 + half] = lsum0;
  Lsum[32 + nl][w * 2 + half] = lsum1;
  __syncthreads();
  if (tid < 64) {
    float s = 0.f;
#pragma unroll
    for (int j = 0; j < 8; ++j) s += Lsum[tid][j];
    Lsum[tid][0] = 1.0f / s;
  }
  __syncthreads();
  {
    const int q = tid >> 2, db = (tid & 3) * 8;
    const float rl = Lsum[q][0];
    bf16x8 o;
#pragma unroll
    for (int dj = 0; dj < 8; ++dj) {
      const float s = Ored[0][db + dj][q] + Ored[1][db + dj][q] +
                      Ored[2][db + dj][q] + Ored[3][db + dj][q];
      o[dj] = (bf16)(s * rl);
    }
    *(bf16x8*)(Og + ((size_t)(b * 4096 + q0 + q)) * 256 + h * 32 + db) = o;
  }
}

// ---------------- K4: out = attn(bf16) @ w_out -> fp32 ----------------
__global__ __launch_bounds__(256) void gemm_out(
    const bf16* __restrict__ A, const bf16* __restrict__ WTo, float* __restrict__ C) {
  const int m0 = blockIdx.x * 64, n0 = blockIdx.y * 128;
  const int tid = threadIdx.x, wave = tid >> 6, lane = tid & 63;
  const int nl = lane & 15, quad = lane >> 4;
  const int arow = m0 + wave * 16 + nl;

  f32x4 zero4 = {0.f, 0.f, 0.f, 0.f};
  f32x4 acc[8];
#pragma unroll
  for (int i = 0; i < 8; ++i) acc[i] = zero4;

  for (int ks = 0; ks < 8; ++ks) {
    bf16x8 af = *(const bf16x8*)(A + (size_t)arow * 256 + ks * 32 + quad * 8);
#pragma unroll
    for (int nf = 0; nf < 8; ++nf) {
      bf16x8 bfr = *(const bf16x8*)(WTo + (size_t)(n0 + nf * 16 + nl) * 256 + ks * 32 + quad * 8);
      acc[nf] = __builtin_amdgcn_mfma_f32_16x16x32_bf16(af, bfr, acc[nf], 0, 0, 0);
    }
  }
  const int Rbase = m0 + wave * 16 + quad * 4;
#pragma unroll
  for (int nf = 0; nf < 8; ++nf)
#pragma unroll
    for (int r = 0; r < 4; ++r)
      C[(size_t)(Rbase + r) * 256 + n0 + nf * 16 + nl] = acc[nf][r];
}

extern "C" void kernel_launch(void* const* d_in, const int* in_sizes, int n_in,
                              void* d_out, int out_size, void* d_ws, size_t ws_size,
                              hipStream_t stream) {
  const float* q  = (const float*)d_in[0];
  const float* k  = (const float*)d_in[1];
  const float* v  = (const float*)d_in[2];
  const int*  mask = (const int*)d_in[3];
  const float* wq = (const float*)d_in[4];
  const float* wk = (const float*)d_in[5];
  const float* wv = (const float*)d_in[6];
  const float* wo = (const float*)d_in[7];
  float* out = (float*)d_out;

  uint8_t* ws = (uint8_t*)d_ws;
  bf16* WT = (bf16*)ws;                               // 512 KB
  bf16* Qp = (bf16*)(ws + (512u << 10));              // frag-native 4 MB
  bf16* Kp = Qp + 2097152;                            // 4 MB
  bf16* Vp = Kp + 2097152;                            // 4 MB
  uint* Mb = (uint*)((uint8_t*)(Vp + 2097152));       // transposed packed mask 4 MB
  bf16* Ao = (bf16*)((uint8_t*)Mb + (4u << 20));      // attn bf16 [B,S,256] 4 MB

  transpose_w<<<dim3(4, 4, 4), 256, 0, stream>>>(wq, wk, wv, wo, WT);
  proj_pack<<<dim3(768 + 8192), 256, 0, stream>>>(q, k, v, WT, Qp, Kp, Vp, mask, Mb);
  attn_kernel<<<dim3(1024), 256, 0, stream>>>(Qp, Kp, Vp, Mb, Ao);
  gemm_out<<<dim3(128, 2), 256, 0, stream>>>(Ao, WT + 3 * 65536, out);
}

// Round 5
// 327.325 us; speedup vs baseline: 1.0832x; 1.0071x over previous
//
#include <hip/hip_runtime.h>
#include <stdint.h>

typedef __bf16 bf16;
typedef __bf16 bf16x8 __attribute__((ext_vector_type(8)));
typedef __bf16 bf16x4 __attribute__((ext_vector_type(4)));
typedef float  f32x4  __attribute__((ext_vector_type(4)));
typedef float  f32x8  __attribute__((ext_vector_type(8)));
typedef float  f32x16 __attribute__((ext_vector_type(16)));
typedef float  float4v __attribute__((ext_vector_type(4)));
typedef int    int4v   __attribute__((ext_vector_type(4)));
typedef unsigned int uint;
typedef unsigned long long ull;

// log2(e)/sqrt(32): folds softmax 1/sqrt(Dh) and e^x -> 2^x into Q scaling
#define QSCALE 0.25505003984214403f

// Fragment-native layout: [bh][blk(128)][sub(4)][lane(32)][8]
//  Q/K: (pos,d) -> blk=pos>>5, sub=d>>3, lane=pos&31, j=d&7
//  V  : (key,d) -> blk=key>>5, sub from key5 bits{4,2}, lane=d, j=g*4+(key5&3), g=(key5>>3)&1
// Mask M2: dword [(b*128+kdw)*4096 + q], bit k5 of kdw*32+k5 vs q.

// ---------------- K0: transpose weights -> bf16 WT[w][n][k] ----------------
__global__ __launch_bounds__(256) void transpose_w(
    const float* __restrict__ w0, const float* __restrict__ w1,
    const float* __restrict__ w2, const float* __restrict__ w3,
    bf16* __restrict__ WT) {
  const int wsel = blockIdx.z;
  const float* W = wsel == 0 ? w0 : wsel == 1 ? w1 : wsel == 2 ? w2 : w3;
  const int k0 = blockIdx.x * 64, n0 = blockIdx.y * 64;
  __shared__ __align__(16) bf16 t[64][72];
  const int tid = threadIdx.x;
  {
    const int kk = (tid >> 4) << 2;
    const int nn = (tid & 15) << 2;
#pragma unroll
    for (int r = 0; r < 4; ++r) {
      float4v a = *(const float4v*)(W + (size_t)(k0 + kk + r) * 256 + n0 + nn);
#pragma unroll
      for (int j = 0; j < 4; ++j) t[nn + j][kk + r] = (bf16)a[j];
    }
  }
  __syncthreads();
  {
    const int ni = tid >> 2;
    const int c  = (tid & 3) * 16;
    bf16x8 o0 = *(const bf16x8*)(&t[ni][c]);
    bf16x8 o1 = *(const bf16x8*)(&t[ni][c + 8]);
    bf16* dst = WT + (size_t)wsel * 65536 + (size_t)(n0 + ni) * 256 + k0 + c;
    *(bf16x8*)dst = o0;
    *(bf16x8*)(dst + 8) = o1;
  }
}

// ---------------- K1: fused proj (blocks 0..767) + pack_mask (768..1279) ----
__global__ __launch_bounds__(256) void proj_pack(
    const float* __restrict__ xq, const float* __restrict__ xk, const float* __restrict__ xv,
    const bf16* __restrict__ WT,
    bf16* __restrict__ Qp, bf16* __restrict__ Kp, bf16* __restrict__ Vp,
    const int* __restrict__ mask, uint* __restrict__ M2) {
  __shared__ __align__(16) unsigned char smem[18432];
  const int tid = threadIdx.x;

  if (blockIdx.x >= 768) {
    // ---- pack_mask: 64 q x 1024 k tile, per-lane pack + LDS dword transpose ----
    uint* trans = (uint*)smem;                    // [32 kdw][72 pitch] dwords
    const int pid = blockIdx.x - 768;             // 512 blocks
    const int bb = pid >> 8;                      // batch
    const int qt = (pid >> 2) & 63, kc = pid & 3;
    const int q0 = qt * 64;
    const int w = tid >> 6, l = tid & 63;
    const int qrow = q0 + w * 16 + (l >> 2);
    const size_t rowbase = ((size_t)(bb * 4096 + qrow)) * 4096 + kc * 1024;
#pragma unroll
    for (int p = 0; p < 8; ++p) {
      const int kdw = p * 4 + (l & 3);            // local dword 0..31
      const int4v* mp = (const int4v*)(mask + rowbase + kdw * 32);
      uint bits = 0;
#pragma unroll
      for (int j = 0; j < 8; ++j) {
        int4v m = mp[j];
#pragma unroll
        for (int i = 0; i < 4; ++i) bits |= (m[i] != 0 ? 1u : 0u) << (j * 4 + i);
      }
      trans[kdw * 72 + w * 16 + (l >> 2)] = bits;
    }
    __syncthreads();
    {
      const int r = tid >> 3, c = (tid & 7) * 4;  // r: kdw row, c: q dword col
      int4v a = *(const int4v*)(trans + r * 72 + c);
      int4v d = *(const int4v*)(trans + r * 72 + c + 32);
      uint* o = M2 + ((size_t)(bb * 128 + kc * 32 + r)) * 4096 + q0;
      *(int4v*)(o + c) = a;
      *(int4v*)(o + c + 32) = d;
    }
    return;
  }

  // ---- proj: 64 pos x 128 cols tile, epilogue through LDS for coalesced stores ----
  const int z = blockIdx.x >> 8;
  const int r8 = blockIdx.x & 255;
  const int m0 = (r8 >> 1) * 64, n0 = (r8 & 1) * 128;
  const float* X = z == 0 ? xq : (z == 1 ? xk : xv);
  const bf16* wt = WT + (size_t)z * 65536;
  const int wave = tid >> 6, lane = tid & 63;
  const int nl = lane & 15, quad = lane >> 4;
  const int arow = m0 + wave * 16 + nl;
  const float* xrow = X + (size_t)arow * 256;

  f32x4 zero4 = {0.f, 0.f, 0.f, 0.f};
  f32x4 acc[8];
#pragma unroll
  for (int i = 0; i < 8; ++i) acc[i] = zero4;

  for (int ks = 0; ks < 8; ++ks) {
    float4v a0 = *(const float4v*)(xrow + ks * 32 + quad * 8);
    float4v a1 = *(const float4v*)(xrow + ks * 32 + quad * 8 + 4);
    bf16x8 af;
#pragma unroll
    for (int i = 0; i < 4; ++i) { af[i] = (bf16)a0[i]; af[4 + i] = (bf16)a1[i]; }
#pragma unroll
    for (int nf = 0; nf < 8; ++nf) {
      bf16x8 bfr = *(const bf16x8*)(wt + (size_t)(n0 + nf * 16 + nl) * 256 + ks * 32 + quad * 8);
      acc[nf] = __builtin_amdgcn_mfma_f32_16x16x32_bf16(af, bfr, acc[nf], 0, 0, 0);
    }
  }

  const int bq = m0 >> 12;          // batch (tile never crosses)
  const int s0 = m0 & 4095;         // seq offset of tile
  const int posl = wave * 16 + quad * 4;

  if (z == 2) {
    // LDS [col(128)][key(64)+pad8] pitch 72, b64 writes of 4 consecutive keys
    bf16* tv = (bf16*)smem;
#pragma unroll
    for (int nf = 0; nf < 8; ++nf) {
      const int col = nf * 16 + nl;
      bf16x4 o;
#pragma unroll
      for (int rr = 0; rr < 4; ++rr) o[rr] = (bf16)acc[nf][rr];
      *(bf16x4*)(tv + (size_t)col * 72 + posl) = o;
    }
    __syncthreads();
    const int h2 = tid >> 6, ln = tid & 63;
    const int d = ln & 31, shalf = ln >> 5;
    const int h = (n0 >> 5) + h2;
    bf16* vb = Vp + (size_t)(bq * 8 + h) * 131072 + (size_t)(s0 >> 5) * 1024 + d * 8;
#pragma unroll
    for (int it = 0; it < 4; ++it) {
      const int blk = it >> 1, sub = (it & 1) * 2 + shalf;
      const int K0 = (sub >> 1) * 16 + (sub & 1) * 4;
      const bf16* src = tv + (size_t)(h2 * 32 + d) * 72 + blk * 32 + K0;
      bf16x4 g0 = *(const bf16x4*)(src);
      bf16x4 g1 = *(const bf16x4*)(src + 8);
      bf16x8 o;
#pragma unroll
      for (int j = 0; j < 4; ++j) { o[j] = g0[j]; o[4 + j] = g1[j]; }
      *(bf16x8*)(vb + (size_t)blk * 1024 + sub * 256) = o;
    }
  } else {
    // LDS [pos(64)][col(128)+pad8] pitch 136, scalar writes, b128 reads
    bf16* tq = (bf16*)smem;
    const float scale = (z == 0) ? QSCALE : 1.0f;
#pragma unroll
    for (int nf = 0; nf < 8; ++nf) {
      const int col = nf * 16 + nl;
#pragma unroll
      for (int rr = 0; rr < 4; ++rr)
        tq[(size_t)(posl + rr) * 136 + col] = (bf16)(acc[nf][rr] * scale);
    }
    __syncthreads();
    bf16* Out = z == 0 ? Qp : Kp;
    const int h2 = tid >> 6, ln = tid & 63;   // ln = local pos
    const int h = (n0 >> 5) + h2;
    const int s = s0 + ln;
    bf16* ob = Out + (size_t)(bq * 8 + h) * 131072 + (size_t)(s >> 5) * 1024 + (s & 31) * 8;
#pragma unroll
    for (int sub = 0; sub < 4; ++sub) {
      bf16x8 o = *(const bf16x8*)(tq + (size_t)ln * 136 + h2 * 32 + sub * 8);
      *(bf16x8*)(ob + sub * 256) = o;
    }
  }
}

// ---------------- K3: attention — 32x32x16, zero LDS in K-loop ----------------
__global__ __launch_bounds__(256) void attn_kernel(
    const bf16* __restrict__ Qp, const bf16* __restrict__ Kp,
    const bf16* __restrict__ Vp, const uint* __restrict__ M2,
    bf16* __restrict__ Og) {
  const int id = blockIdx.x;
  const int xcd = id & 7, slot = id >> 3;
  const int bh = xcd * 2 + (slot >> 6);      // 2 bh per XCD -> L2-resident K/V/mask
  const int q0 = (slot & 63) * 64;
  const int b = bh >> 3, h = bh & 7;
  const int tid = threadIdx.x, w = tid >> 6, lane = tid & 63;
  const int nl = lane & 31, half = lane >> 5;

  __shared__ float Ored[4][32][66];
  __shared__ float Lsum[64][8];

  const size_t bhbase = (size_t)bh * 131072;
  const int so0 = half * 256 + nl * 8;
  const int so1 = 512 + half * 256 + nl * 8;

  bf16x8 qf[2][2];
#pragma unroll
  for (int qt = 0; qt < 2; ++qt) {
    const bf16* qb = Qp + bhbase + (size_t)((q0 >> 5) + qt) * 1024;
    qf[qt][0] = *(const bf16x8*)(qb + so0);
    qf[qt][1] = *(const bf16x8*)(qb + so1);
  }

  const bf16* Kw = Kp + bhbase + (size_t)w * 1024;
  const bf16* Vw = Vp + bhbase + (size_t)w * 1024;
  const uint* Mw = M2 + (size_t)b * 524288 + (size_t)w * 4096 + q0 + nl;

  f32x16 z16;
#pragma unroll
  for (int i = 0; i < 16; ++i) z16[i] = 0.f;
  f32x16 acc0 = z16, acc1 = z16;
  float lsum0 = 0.f, lsum1 = 0.f;

  struct Frag { bf16x8 ka0, ka1, va0, va1; uint m0, m1; };
  auto LOADF = [&](int kt) -> Frag {
    Frag f;
    const bf16* kc = Kw + (size_t)kt * 4096;
    const bf16* vc = Vw + (size_t)kt * 4096;
    f.ka0 = *(const bf16x8*)(kc + so0);
    f.ka1 = *(const bf16x8*)(kc + so1);
    f.va0 = *(const bf16x8*)(vc + so0);
    f.va1 = *(const bf16x8*)(vc + so1);
    const uint* mp = Mw + (size_t)kt * 16384;
    f.m0 = mp[0];
    f.m1 = mp[32];
    return f;
  };

  auto STEP = [&](const Frag& f) {
    const int minv0 = (int)((~f.m0) >> (4 * half));
    const int minv1 = (int)((~f.m1) >> (4 * half));
    f32x16 st0 = __builtin_amdgcn_mfma_f32_32x32x16_bf16(f.ka0, qf[0][0], z16, 0, 0, 0);
    st0 = __builtin_amdgcn_mfma_f32_32x32x16_bf16(f.ka1, qf[0][1], st0, 0, 0, 0);
    f32x16 st1 = __builtin_amdgcn_mfma_f32_32x32x16_bf16(f.ka0, qf[1][0], z16, 0, 0, 0);
    st1 = __builtin_amdgcn_mfma_f32_32x32x16_bf16(f.ka1, qf[1][1], st1, 0, 0, 0);

    f32x16 pf0, pf1;
#pragma unroll
    for (int g = 0; g < 4; ++g)
#pragma unroll
      for (int r = 0; r < 4; ++r) {
        const int i = g * 4 + r, off = r + 8 * g;
        float e0 = __builtin_amdgcn_exp2f(st0[i]);
        float e1 = __builtin_amdgcn_exp2f(st1[i]);
        const uint k0m = (uint)__builtin_amdgcn_sbfe(minv0, off, 1);
        const uint k1m = (uint)__builtin_amdgcn_sbfe(minv1, off, 1);
        e0 = __uint_as_float(__float_as_uint(e0) & k0m);
        e1 = __uint_as_float(__float_as_uint(e1) & k1m);
        lsum0 += e0; lsum1 += e1;
        pf0[i] = e0; pf1[i] = e1;
      }
    const bf16x8 pb00 = __builtin_convertvector(
        __builtin_shufflevector(pf0, pf0, 0, 1, 2, 3, 4, 5, 6, 7), bf16x8);
    const bf16x8 pb01 = __builtin_convertvector(
        __builtin_shufflevector(pf0, pf0, 8, 9, 10, 11, 12, 13, 14, 15), bf16x8);
    const bf16x8 pb10 = __builtin_convertvector(
        __builtin_shufflevector(pf1, pf1, 0, 1, 2, 3, 4, 5, 6, 7), bf16x8);
    const bf16x8 pb11 = __builtin_convertvector(
        __builtin_shufflevector(pf1, pf1, 8, 9, 10, 11, 12, 13, 14, 15), bf16x8);

    acc0 = __builtin_amdgcn_mfma_f32_32x32x16_bf16(f.va0, pb00, acc0, 0, 0, 0);
    acc0 = __builtin_amdgcn_mfma_f32_32x32x16_bf16(f.va1, pb01, acc0, 0, 0, 0);
    acc1 = __builtin_amdgcn_mfma_f32_32x32x16_bf16(f.va0, pb10, acc1, 0, 0, 0);
    acc1 = __builtin_amdgcn_mfma_f32_32x32x16_bf16(f.va1, pb11, acc1, 0, 0, 0);
  };

  Frag fa = LOADF(0), fb;
  for (int kt = 0; kt < 32; kt += 2) {
    fb = LOADF(kt + 1);
    STEP(fa);
    if (kt + 2 < 32) fa = LOADF(kt + 2);
    STEP(fb);
  }

  // ---- epilogue: cross-wave reduce ----
#pragma unroll
  for (int g = 0; g < 4; ++g)
#pragma unroll
    for (int r = 0; r < 4; ++r) {
      const int d = r + 8 * g + 4 * half, i = g * 4 + r;
      Ored[w][d][nl] = acc0[i];
      Ored[w][d][32 + nl] = acc1[i];
    }
  Lsum[nl][w * 2 + half] = lsum0;
  Lsum[32 + nl][w * 2 + half] = lsum1;
  __syncthreads();
  if (tid < 64) {
    float s = 0.f;
#pragma unroll
    for (int j = 0; j < 8; ++j) s += Lsum[tid][j];
    Lsum[tid][0] = 1.0f / s;
  }
  __syncthreads();
  {
    const int q = tid >> 2, db = (tid & 3) * 8;
    const float rl = Lsum[q][0];
    bf16x8 o;
#pragma unroll
    for (int dj = 0; dj < 8; ++dj) {
      const float s = Ored[0][db + dj][q] + Ored[1][db + dj][q] +
                      Ored[2][db + dj][q] + Ored[3][db + dj][q];
      o[dj] = (bf16)(s * rl);
    }
    *(bf16x8*)(Og + ((size_t)(b * 4096 + q0 + q)) * 256 + h * 32 + db) = o;
  }
}

// ---------------- K4: out = attn(bf16) @ w_out -> fp32, 64x64 tiles ----------------
__global__ __launch_bounds__(256) void gemm_out(
    const bf16* __restrict__ A, const bf16* __restrict__ WTo, float* __restrict__ C) {
  const int m0 = blockIdx.x * 64, n0 = blockIdx.y * 64;
  const int tid = threadIdx.x, wave = tid >> 6, lane = tid & 63;
  const int nl = lane & 15, quad = lane >> 4;
  const int arow = m0 + wave * 16 + nl;

  f32x4 zero4 = {0.f, 0.f, 0.f, 0.f};
  f32x4 acc[4];
#pragma unroll
  for (int i = 0; i < 4; ++i) acc[i] = zero4;

  for (int ks = 0; ks < 8; ++ks) {
    bf16x8 af = *(const bf16x8*)(A + (size_t)arow * 256 + ks * 32 + quad * 8);
#pragma unroll
    for (int nf = 0; nf < 4; ++nf) {
      bf16x8 bfr = *(const bf16x8*)(WTo + (size_t)(n0 + nf * 16 + nl) * 256 + ks * 32 + quad * 8);
      acc[nf] = __builtin_amdgcn_mfma_f32_16x16x32_bf16(af, bfr, acc[nf], 0, 0, 0);
    }
  }
  const int Rbase = m0 + wave * 16 + quad * 4;
#pragma unroll
  for (int nf = 0; nf < 4; ++nf)
#pragma unroll
    for (int r = 0; r < 4; ++r)
      C[(size_t)(Rbase + r) * 256 + n0 + nf * 16 + nl] = acc[nf][r];
}

extern "C" void kernel_launch(void* const* d_in, const int* in_sizes, int n_in,
                              void* d_out, int out_size, void* d_ws, size_t ws_size,
                              hipStream_t stream) {
  const float* q  = (const float*)d_in[0];
  const float* k  = (const float*)d_in[1];
  const float* v  = (const float*)d_in[2];
  const int*  mask = (const int*)d_in[3];
  const float* wq = (const float*)d_in[4];
  const float* wk = (const float*)d_in[5];
  const float* wv = (const float*)d_in[6];
  const float* wo = (const float*)d_in[7];
  float* out = (float*)d_out;

  uint8_t* ws = (uint8_t*)d_ws;
  bf16* WT = (bf16*)ws;                               // 512 KB
  bf16* Qp = (bf16*)(ws + (512u << 10));              // frag-native 4 MB
  bf16* Kp = Qp + 2097152;                            // 4 MB
  bf16* Vp = Kp + 2097152;                            // 4 MB
  uint* Mb = (uint*)((uint8_t*)(Vp + 2097152));       // transposed packed mask 4 MB
  bf16* Ao = (bf16*)((uint8_t*)Mb + (4u << 20));      // attn bf16 [B,S,256] 4 MB

  transpose_w<<<dim3(4, 4, 4), 256, 0, stream>>>(wq, wk, wv, wo, WT);
  proj_pack<<<dim3(768 + 512), 256, 0, stream>>>(q, k, v, WT, Qp, Kp, Vp, mask, Mb);
  attn_kernel<<<dim3(1024), 256, 0, stream>>>(Qp, Kp, Vp, Mb, Ao);
  gemm_out<<<dim3(128, 4), 256, 0, stream>>>(Ao, WT + 3 * 65536, out);
}